// Round 1
// baseline (7635.411 us; speedup 1.0000x reference)
//
#include <hip/hip_runtime.h>
#include <math.h>

#define BQ 4
#define LQ 1024
#define DM 256
#define DI 512
#define NS 16
#define DTR 16
#define KC 4
#define NL 8

static __device__ __forceinline__ float sigmoidf_(float x) { return 1.0f / (1.0f + expf(-x)); }
static __device__ __forceinline__ float siluf_(float x) { return x * sigmoidf_(x); }
static __device__ __forceinline__ float softplusf_(float x) {
    return fmaxf(x, 0.0f) + log1pf(expf(-fabsf(x)));
}

// ---------------- embed: h[b,l,0:128] = x@W_embed + b_embed ; h[b,l,128:256] = pos_enc[l]
__global__ void k_embed(const float* __restrict__ x, const float* __restrict__ pos,
                        const float* __restrict__ We, const float* __restrict__ be,
                        float* __restrict__ h) {
    int idx = blockIdx.x * 256 + threadIdx.x;  // B*L*DM
    int d = idx % DM;
    int l = (idx / DM) % LQ;
    int b = idx / (DM * LQ);
    float v;
    if (d < 128) {
        float x0 = x[(b * LQ + l) * 2 + 0];
        float x1 = x[(b * LQ + l) * 2 + 1];
        v = fmaf(x0, We[d], fmaf(x1, We[128 + d], be[d]));
    } else {
        v = pos[l * 128 + (d - 128)];
    }
    h[idx] = v;
}

// ---------------- rmsnorm: one wave per row of 256
__global__ __launch_bounds__(256) void k_rmsnorm(const float* __restrict__ h,
                                                 const float* __restrict__ w,
                                                 float* __restrict__ xn) {
    int row = blockIdx.x * 4 + (threadIdx.x >> 6);
    int lane = threadIdx.x & 63;
    float4 v = ((const float4*)(h + (size_t)row * DM))[lane];
    float ss = v.x * v.x + v.y * v.y + v.z * v.z + v.w * v.w;
#pragma unroll
    for (int off = 32; off; off >>= 1) ss += __shfl_xor(ss, off);
    float scale = 1.0f / sqrtf(ss * (1.0f / DM) + 1e-5f);
    float4 wv = ((const float4*)w)[lane];
    float4 o;
    o.x = v.x * scale * wv.x;
    o.y = v.y * scale * wv.y;
    o.z = v.z * scale * wv.z;
    o.w = v.w * scale * wv.w;
    ((float4*)(xn + (size_t)row * DM))[lane] = o;
}

// ---------------- generic fp32 tiled GEMM: C = A(MxK) @ B(KxN) [+ Res]
template <int RES>
__global__ __launch_bounds__(256) void k_gemm64(const float* __restrict__ A,
                                                const float* __restrict__ Bw,
                                                const float* __restrict__ Res,
                                                float* __restrict__ C, int M, int N, int K) {
    __shared__ float As[16][64];
    __shared__ float Bs[16][64];
    int bm = blockIdx.y * 64, bn = blockIdx.x * 64;
    int tid = threadIdx.x;
    int tr = tid >> 4, tc = tid & 15;        // compute mapping: 16x16 threads of 4x4
    int arow = tid >> 2, akq = tid & 3;      // A load: 64 rows x 4 float4
    int brow = tid >> 4, bnq = tid & 15;     // B load: 16 rows x 16 float4
    float acc[4][4] = {};
    for (int k0 = 0; k0 < K; k0 += 16) {
        float4 av = *(const float4*)(A + (size_t)(bm + arow) * K + k0 + akq * 4);
        float4 bv = *(const float4*)(Bw + (size_t)(k0 + brow) * N + bn + bnq * 4);
        __syncthreads();
        As[akq * 4 + 0][arow] = av.x;
        As[akq * 4 + 1][arow] = av.y;
        As[akq * 4 + 2][arow] = av.z;
        As[akq * 4 + 3][arow] = av.w;
        *(float4*)&Bs[brow][bnq * 4] = bv;
        __syncthreads();
#pragma unroll
        for (int kk = 0; kk < 16; ++kk) {
            const float4 a = *(const float4*)&As[kk][tr * 4];
            const float4 b = *(const float4*)&Bs[kk][tc * 4];
            const float ar[4] = {a.x, a.y, a.z, a.w};
            const float br[4] = {b.x, b.y, b.z, b.w};
#pragma unroll
            for (int i = 0; i < 4; i++)
#pragma unroll
                for (int j = 0; j < 4; j++) acc[i][j] = fmaf(ar[i], br[j], acc[i][j]);
        }
    }
#pragma unroll
    for (int i = 0; i < 4; i++) {
        size_t off = (size_t)(bm + tr * 4 + i) * N + bn + tc * 4;
        float4 o = {acc[i][0], acc[i][1], acc[i][2], acc[i][3]};
        if (RES) {
            float4 r = *(const float4*)(Res + off);
            o.x += r.x; o.y += r.y; o.z += r.z; o.w += r.w;
        }
        *(float4*)(C + off) = o;
    }
}

// ---------------- causal depthwise conv (K=4) + SiLU. reads hid part of xg (cols 0..511)
__global__ void k_conv(const float* __restrict__ xg, const float* __restrict__ cw,
                       const float* __restrict__ cb, float* __restrict__ hs) {
    int idx = blockIdx.x * 256 + threadIdx.x;  // B*L*DI
    int d = idx % DI;
    int l = (idx / DI) % LQ;
    int b = idx / (DI * LQ);
    const float* base = xg + ((size_t)b * LQ) * 1024 + d;
    float acc = cb[d];
#pragma unroll
    for (int k = 0; k < KC; k++) {
        int ls = l - (KC - 1) + k;
        if (ls >= 0) acc = fmaf(base[(size_t)ls * 1024], cw[d * KC + k], acc);
    }
    hs[idx] = siluf_(acc);
}

// ---------------- sp = hs(4096x512) @ W_x(512x48)  — thread per output
__global__ void k_sp(const float* __restrict__ hs, const float* __restrict__ Wx,
                     float* __restrict__ sp) {
    int idx = blockIdx.x * 256 + threadIdx.x;  // B*L*48
    int j = idx % 48;
    int row = idx / 48;
    const float* a = hs + (size_t)row * DI;
    float acc = 0.f;
#pragma unroll 8
    for (int k = 0; k < DI; k++) acc = fmaf(a[k], Wx[k * 48 + j], acc);
    sp[idx] = acc;
}

// ---------------- delta = softplus(dt(4096x16) @ W_dt(16x512) + b_dt)
__global__ void k_delta(const float* __restrict__ sp, const float* __restrict__ Wdt,
                        const float* __restrict__ bdt, float* __restrict__ delta) {
    int idx = blockIdx.x * 256 + threadIdx.x;  // B*L*DI
    int d = idx % DI;
    int row = idx / DI;
    const float* dt = sp + (size_t)row * 48;
    float acc = bdt[d];
#pragma unroll
    for (int k = 0; k < DTR; k++) acc = fmaf(dt[k], Wdt[k * DI + d], acc);
    delta[idx] = softplusf_(acc);
}

// ---------------- selective scan: thread per (b,d,n); 16-lane reduce for y
__global__ __launch_bounds__(256) void k_scan(const float* __restrict__ delta,
                                              const float* __restrict__ hs,
                                              const float* __restrict__ sp,
                                              const float* __restrict__ xg,
                                              const float* __restrict__ Alog,
                                              const float* __restrict__ Dsk,
                                              float* __restrict__ y) {
    int tid = threadIdx.x;
    int g = blockIdx.x * 16 + (tid >> 4);  // group id 0..2047
    int n = tid & 15;
    int d = g % DI;
    int b = g / DI;
    float Av = -expf(Alog[d * NS + n]);
    float Dv = Dsk[d];
    float hstate = 0.f;
    const float* dp = delta + ((size_t)b * LQ) * DI + d;
    const float* up = hs + ((size_t)b * LQ) * DI + d;
    const float* spB = sp + ((size_t)b * LQ) * 48 + DTR + n;
    const float* spC = spB + NS;
    const float* gp = xg + ((size_t)b * LQ) * 1024 + DI + d;
    float* yp = y + ((size_t)b * LQ) * DI + d;
#pragma unroll 4
    for (int l = 0; l < LQ; ++l) {
        float dv = dp[(size_t)l * DI];
        float u = up[(size_t)l * DI];
        float Bv = spB[(size_t)l * 48];
        float Cv = spC[(size_t)l * 48];
        float dA = expf(dv * Av);
        hstate = fmaf(dA, hstate, dv * Bv * u);
        float p = hstate * Cv;
        p += __shfl_xor(p, 1);
        p += __shfl_xor(p, 2);
        p += __shfl_xor(p, 4);
        p += __shfl_xor(p, 8);
        if (n == 0) {
            float gv = gp[(size_t)l * 1024];
            yp[(size_t)l * DI] = (p + u * Dv) * gv * sigmoidf_(gv);
        }
    }
}

// ---------------- head: out[row] = {h·W_amp + b_amp, tanh(h·W_phase + b_phase)}
__global__ __launch_bounds__(256) void k_head(const float* __restrict__ h,
                                              const float* __restrict__ Wa,
                                              const float* __restrict__ ba,
                                              const float* __restrict__ Wp,
                                              const float* __restrict__ bp,
                                              float* __restrict__ out) {
    int row = blockIdx.x * 4 + (threadIdx.x >> 6);
    int lane = threadIdx.x & 63;
    float4 v = ((const float4*)(h + (size_t)row * DM))[lane];
    float4 wa = ((const float4*)Wa)[lane];
    float4 wp = ((const float4*)Wp)[lane];
    float sa = v.x * wa.x + v.y * wa.y + v.z * wa.z + v.w * wa.w;
    float sph = v.x * wp.x + v.y * wp.y + v.z * wp.z + v.w * wp.w;
#pragma unroll
    for (int off = 32; off; off >>= 1) {
        sa += __shfl_xor(sa, off);
        sph += __shfl_xor(sph, off);
    }
    if (lane == 0) {
        out[(size_t)row * 2 + 0] = sa + ba[0];
        out[(size_t)row * 2 + 1] = tanhf(sph + bp[0]);
    }
}

extern "C" void kernel_launch(void* const* d_in, const int* in_sizes, int n_in,
                              void* d_out, int out_size, void* d_ws, size_t ws_size,
                              hipStream_t stream) {
    const float* x = (const float*)d_in[0];
    const float* pos = (const float*)d_in[1];
    const float* We = (const float*)d_in[2];
    const float* be = (const float*)d_in[3];
    const float* ln_w = (const float*)d_in[4];
    const float* W_in = (const float*)d_in[5];
    const float* conv_w = (const float*)d_in[6];
    const float* conv_b = (const float*)d_in[7];
    const float* W_x = (const float*)d_in[8];
    const float* W_dt = (const float*)d_in[9];
    const float* b_dt = (const float*)d_in[10];
    const float* A_log = (const float*)d_in[11];
    const float* D_skip = (const float*)d_in[12];
    const float* W_out = (const float*)d_in[13];
    const float* Wa = (const float*)d_in[14];
    const float* ba = (const float*)d_in[15];
    const float* Wp = (const float*)d_in[16];
    const float* bp = (const float*)d_in[17];

    float* ws = (float*)d_ws;
    float* h = ws;                      // 1,048,576
    float* xny = h + 1048576;           // 2,097,152 (xn aliases first half; y uses all)
    float* xg = xny + 2097152;          // 4,194,304
    float* hs = xg + 4194304;           // 2,097,152
    float* delta = hs + 2097152;        // 2,097,152
    float* sp = delta + 2097152;        // 196,608
    float* xn = xny;
    float* y = xny;

    k_embed<<<4096, 256, 0, stream>>>(x, pos, We, be, h);
    for (int i = 0; i < NL; i++) {
        k_rmsnorm<<<1024, 256, 0, stream>>>(h, ln_w + i * DM, xn);
        dim3 g1(1024 / 64, 4096 / 64);
        k_gemm64<0><<<g1, 256, 0, stream>>>(xn, W_in + (size_t)i * DM * 2 * DI, nullptr, xg,
                                            4096, 1024, 256);
        k_conv<<<8192, 256, 0, stream>>>(xg, conv_w + i * DI * KC, conv_b + i * DI, hs);
        k_sp<<<768, 256, 0, stream>>>(hs, W_x + (size_t)i * DI * 48, sp);
        k_delta<<<8192, 256, 0, stream>>>(sp, W_dt + i * DTR * DI, b_dt + i * DI, delta);
        k_scan<<<128, 256, 0, stream>>>(delta, hs, sp, xg, A_log + i * DI * NS,
                                        D_skip + i * DI, y);
        dim3 g4(256 / 64, 4096 / 64);
        k_gemm64<1><<<g4, 256, 0, stream>>>(y, W_out + (size_t)i * DI * DM, h, h,
                                            4096, 256, 512);
    }
    k_head<<<1024, 256, 0, stream>>>(h, Wa, ba, Wp, bp, (float*)d_out);
}

// Round 2
// 1471.923 us; speedup vs baseline: 5.1874x; 5.1874x over previous
//
#include <hip/hip_runtime.h>
#include <math.h>

#define BQ 4
#define LQ 1024
#define DM 256
#define DI 512
#define NS 16
#define DTR 16
#define KC 4
#define NL 8

static __device__ __forceinline__ float sigmoidf_(float x) { return 1.0f / (1.0f + expf(-x)); }
static __device__ __forceinline__ float siluf_(float x) { return x * sigmoidf_(x); }
static __device__ __forceinline__ float softplusf_(float x) {
    return fmaxf(x, 0.0f) + log1pf(expf(-fabsf(x)));
}

// ---------------- embed
__global__ void k_embed(const float* __restrict__ x, const float* __restrict__ pos,
                        const float* __restrict__ We, const float* __restrict__ be,
                        float* __restrict__ h) {
    int idx = blockIdx.x * 256 + threadIdx.x;  // B*L*DM
    int d = idx % DM;
    int l = (idx / DM) % LQ;
    int b = idx / (DM * LQ);
    float v;
    if (d < 128) {
        float x0 = x[(b * LQ + l) * 2 + 0];
        float x1 = x[(b * LQ + l) * 2 + 1];
        v = fmaf(x0, We[d], fmaf(x1, We[128 + d], be[d]));
    } else {
        v = pos[l * 128 + (d - 128)];
    }
    h[idx] = v;
}

// ---------------- rmsnorm: one wave per row of 256
__global__ __launch_bounds__(256) void k_rmsnorm(const float* __restrict__ h,
                                                 const float* __restrict__ w,
                                                 float* __restrict__ xn) {
    int row = blockIdx.x * 4 + (threadIdx.x >> 6);
    int lane = threadIdx.x & 63;
    float4 v = ((const float4*)(h + (size_t)row * DM))[lane];
    float ss = v.x * v.x + v.y * v.y + v.z * v.z + v.w * v.w;
#pragma unroll
    for (int off = 32; off; off >>= 1) ss += __shfl_xor(ss, off);
    float scale = 1.0f / sqrtf(ss * (1.0f / DM) + 1e-5f);
    float4 wv = ((const float4*)w)[lane];
    float4 o;
    o.x = v.x * scale * wv.x;
    o.y = v.y * scale * wv.y;
    o.z = v.z * scale * wv.z;
    o.w = v.w * scale * wv.w;
    ((float4*)(xn + (size_t)row * DM))[lane] = o;
}

// ---------------- generic fp32 tiled GEMM: C = A(MxK) @ B(KxN) [+ Res]
template <int RES>
__global__ __launch_bounds__(256) void k_gemm64(const float* __restrict__ A,
                                                const float* __restrict__ Bw,
                                                const float* __restrict__ Res,
                                                float* __restrict__ C, int M, int N, int K) {
    __shared__ float As[16][64];
    __shared__ float Bs[16][64];
    int bm = blockIdx.y * 64, bn = blockIdx.x * 64;
    int tid = threadIdx.x;
    int tr = tid >> 4, tc = tid & 15;
    int arow = tid >> 2, akq = tid & 3;
    int brow = tid >> 4, bnq = tid & 15;
    float acc[4][4] = {};
    for (int k0 = 0; k0 < K; k0 += 16) {
        float4 av = *(const float4*)(A + (size_t)(bm + arow) * K + k0 + akq * 4);
        float4 bv = *(const float4*)(Bw + (size_t)(k0 + brow) * N + bn + bnq * 4);
        __syncthreads();
        As[akq * 4 + 0][arow] = av.x;
        As[akq * 4 + 1][arow] = av.y;
        As[akq * 4 + 2][arow] = av.z;
        As[akq * 4 + 3][arow] = av.w;
        *(float4*)&Bs[brow][bnq * 4] = bv;
        __syncthreads();
#pragma unroll
        for (int kk = 0; kk < 16; ++kk) {
            const float4 a = *(const float4*)&As[kk][tr * 4];
            const float4 b = *(const float4*)&Bs[kk][tc * 4];
            const float ar[4] = {a.x, a.y, a.z, a.w};
            const float br[4] = {b.x, b.y, b.z, b.w};
#pragma unroll
            for (int i = 0; i < 4; i++)
#pragma unroll
                for (int j = 0; j < 4; j++) acc[i][j] = fmaf(ar[i], br[j], acc[i][j]);
        }
    }
#pragma unroll
    for (int i = 0; i < 4; i++) {
        size_t off = (size_t)(bm + tr * 4 + i) * N + bn + tc * 4;
        float4 o = {acc[i][0], acc[i][1], acc[i][2], acc[i][3]};
        if (RES) {
            float4 r = *(const float4*)(Res + off);
            o.x += r.x; o.y += r.y; o.z += r.z; o.w += r.w;
        }
        *(float4*)(C + off) = o;
    }
}

// ---------------- tiled transpose + causal depthwise conv (K=4) + SiLU
// reads xg[b,l,0:512]; writes hs [b,l,d] AND hsT [b,d,l]
__global__ __launch_bounds__(256) void k_convT(const float* __restrict__ xg,
                                               const float* __restrict__ cw,
                                               const float* __restrict__ cb,
                                               float* __restrict__ hs,
                                               float* __restrict__ hsT) {
    int l0 = blockIdx.x * 32, d0 = blockIdx.y * 64, b = blockIdx.z;
    __shared__ float xs[35][68];
    __shared__ float cs[32][68];
    int tid = threadIdx.x;
    for (int idx = tid; idx < 35 * 16; idx += 256) {
        int r = idx >> 4, q = idx & 15;
        int l = l0 - 3 + r;
        float4 v = {0.f, 0.f, 0.f, 0.f};
        if (l >= 0) v = *(const float4*)(xg + ((size_t)(b * LQ + l)) * 1024 + d0 + q * 4);
        *(float4*)&xs[r][q * 4] = v;
    }
    __syncthreads();
    int dl = tid >> 2, lq = tid & 3;  // dl 0..63, lq 0..3 (8 l each)
    const float* w = cw + (d0 + dl) * KC;
    float w0 = w[0], w1 = w[1], w2 = w[2], w3 = w[3];
    float bb = cb[d0 + dl];
    float out[8];
    float x0 = xs[lq * 8 + 0][dl];
    float x1 = xs[lq * 8 + 1][dl];
    float x2 = xs[lq * 8 + 2][dl];
#pragma unroll
    for (int j = 0; j < 8; ++j) {
        float x3 = xs[lq * 8 + 3 + j][dl];
        float v = fmaf(w0, x0, fmaf(w1, x1, fmaf(w2, x2, fmaf(w3, x3, bb))));
        out[j] = siluf_(v);
        x0 = x1; x1 = x2; x2 = x3;
    }
    size_t to = ((size_t)(b * DI + d0 + dl)) * LQ + l0 + lq * 8;
    float4 o0 = {out[0], out[1], out[2], out[3]};
    float4 o1 = {out[4], out[5], out[6], out[7]};
    *(float4*)(hsT + to) = o0;
    *(float4*)(hsT + to + 4) = o1;
#pragma unroll
    for (int j = 0; j < 8; ++j) cs[lq * 8 + j][dl] = out[j];
    __syncthreads();
    for (int idx = tid; idx < 32 * 16; idx += 256) {
        int r = idx >> 4, q = idx & 15;
        *(float4*)(hs + ((size_t)(b * LQ + l0 + r)) * DI + d0 + q * 4) =
            *(const float4*)&cs[r][q * 4];
    }
}

// ---------------- sp = hs(4096x512) @ W_x(512x48)
__global__ void k_sp(const float* __restrict__ hs, const float* __restrict__ Wx,
                     float* __restrict__ sp) {
    int idx = blockIdx.x * 256 + threadIdx.x;  // B*L*48
    int j = idx % 48;
    int row = idx / 48;
    const float* a = hs + (size_t)row * DI;
    float acc = 0.f;
#pragma unroll 8
    for (int k = 0; k < DI; k++) acc = fmaf(a[k], Wx[k * 48 + j], acc);
    sp[idx] = acc;
}

// ---------------- deltaT[b,d,l] = softplus(dt(row) @ W_dt + b_dt)
__global__ void k_deltaT(const float* __restrict__ sp, const float* __restrict__ Wdt,
                         const float* __restrict__ bdt, float* __restrict__ deltaT) {
    int idx = blockIdx.x * 256 + threadIdx.x;  // (b*512+d)*1024 + l
    int l = idx & 1023;
    int d = (idx >> 10) & 511;
    int b = idx >> 19;
    const float4* dt4 = (const float4*)(sp + ((size_t)(b * LQ + l)) * 48);
    float4 t0 = dt4[0], t1 = dt4[1], t2 = dt4[2], t3 = dt4[3];
    float acc = bdt[d];
    acc = fmaf(t0.x, Wdt[0 * DI + d], acc);
    acc = fmaf(t0.y, Wdt[1 * DI + d], acc);
    acc = fmaf(t0.z, Wdt[2 * DI + d], acc);
    acc = fmaf(t0.w, Wdt[3 * DI + d], acc);
    acc = fmaf(t1.x, Wdt[4 * DI + d], acc);
    acc = fmaf(t1.y, Wdt[5 * DI + d], acc);
    acc = fmaf(t1.z, Wdt[6 * DI + d], acc);
    acc = fmaf(t1.w, Wdt[7 * DI + d], acc);
    acc = fmaf(t2.x, Wdt[8 * DI + d], acc);
    acc = fmaf(t2.y, Wdt[9 * DI + d], acc);
    acc = fmaf(t2.z, Wdt[10 * DI + d], acc);
    acc = fmaf(t2.w, Wdt[11 * DI + d], acc);
    acc = fmaf(t3.x, Wdt[12 * DI + d], acc);
    acc = fmaf(t3.y, Wdt[13 * DI + d], acc);
    acc = fmaf(t3.z, Wdt[14 * DI + d], acc);
    acc = fmaf(t3.w, Wdt[15 * DI + d], acc);
    deltaT[idx] = softplusf_(acc);
}

// ---------------- scan phase A: per-chunk (prod dA, local state)
__global__ __launch_bounds__(256) void k_scanA(const float* __restrict__ deltaT,
                                               const float* __restrict__ hsT,
                                               const float* __restrict__ sp,
                                               const float* __restrict__ Alog,
                                               float2* __restrict__ PS) {
    int c = blockIdx.x, dt4 = blockIdx.y, b = blockIdx.z;
    int tid = threadIdx.x;
    int dl = tid >> 4, n = tid & 15;
    int d = dt4 * 16 + dl;
    int l0 = c * 64;
    __shared__ float Bs[64][16];
    {
        int r = tid >> 2, q = tid & 3;
        float4 v = *(const float4*)(sp + ((size_t)(b * LQ + l0 + r)) * 48 + DTR + q * 4);
        *(float4*)&Bs[r][q * 4] = v;
    }
    float Av = -expf(Alog[d * NS + n]);
    const float* dp = deltaT + ((size_t)(b * DI + d)) * LQ + l0;
    const float* up = hsT + ((size_t)(b * DI + d)) * LQ + l0;
    __syncthreads();
    float hst = 0.f, P = 1.f;
#pragma unroll 2
    for (int lq = 0; lq < 16; ++lq) {
        float4 df = *(const float4*)(dp + lq * 4);
        float4 uf = *(const float4*)(up + lq * 4);
        float dv[4] = {df.x, df.y, df.z, df.w};
        float uv[4] = {uf.x, uf.y, uf.z, uf.w};
#pragma unroll
        for (int j = 0; j < 4; ++j) {
            float dA = __expf(dv[j] * Av);
            hst = fmaf(dA, hst, dv[j] * Bs[lq * 4 + j][n] * uv[j]);
            P *= dA;
        }
    }
    PS[((size_t)(b * 16 + c)) * 8192 + d * 16 + n] = make_float2(P, hst);
}

// ---------------- scan phase B: combine chunk states (serial over 16 chunks)
__global__ void k_scanB(const float2* __restrict__ PS, float* __restrict__ hin) {
    int idx = blockIdx.x * 256 + threadIdx.x;  // b*8192 + dn
    int b = idx >> 13, dn = idx & 8191;
    float hst = 0.f;
#pragma unroll
    for (int c = 0; c < 16; ++c) {
        size_t o = ((size_t)(b * 16 + c)) * 8192 + dn;
        hin[o] = hst;
        float2 ps = PS[o];
        hst = fmaf(ps.x, hst, ps.y);
    }
}

// ---------------- scan phase C: replay with correct init, emit y
__global__ __launch_bounds__(256) void k_scanC(const float* __restrict__ deltaT,
                                               const float* __restrict__ hsT,
                                               const float* __restrict__ sp,
                                               const float* __restrict__ xg,
                                               const float* __restrict__ hin,
                                               const float* __restrict__ Alog,
                                               const float* __restrict__ Dsk,
                                               float* __restrict__ y) {
    int c = blockIdx.x, dt4 = blockIdx.y, b = blockIdx.z;
    int tid = threadIdx.x;
    int dl = tid >> 4, n = tid & 15;
    int d = dt4 * 16 + dl;
    int l0 = c * 64;
    __shared__ float BCs[64][32];
    __shared__ float yt[64][16];
    for (int idx = tid; idx < 64 * 8; idx += 256) {
        int r = idx >> 3, q = idx & 7;
        float4 v = *(const float4*)(sp + ((size_t)(b * LQ + l0 + r)) * 48 + DTR + q * 4);
        *(float4*)&BCs[r][q * 4] = v;
    }
    float Av = -expf(Alog[d * NS + n]);
    float Dv = Dsk[d];
    float hst = hin[((size_t)(b * 16 + c)) * 8192 + d * 16 + n];
    const float* dp = deltaT + ((size_t)(b * DI + d)) * LQ + l0;
    const float* up = hsT + ((size_t)(b * DI + d)) * LQ + l0;
    const float* gp = xg + ((size_t)(b * LQ + l0)) * 1024 + DI + d;
    __syncthreads();
#pragma unroll 2
    for (int lq = 0; lq < 16; ++lq) {
        float4 df = *(const float4*)(dp + lq * 4);
        float4 uf = *(const float4*)(up + lq * 4);
        float dv[4] = {df.x, df.y, df.z, df.w};
        float uv[4] = {uf.x, uf.y, uf.z, uf.w};
#pragma unroll
        for (int j = 0; j < 4; ++j) {
            int l = lq * 4 + j;
            float dA = __expf(dv[j] * Av);
            hst = fmaf(dA, hst, dv[j] * BCs[l][n] * uv[j]);
            float p = hst * BCs[l][16 + n];
            p += __shfl_xor(p, 1);
            p += __shfl_xor(p, 2);
            p += __shfl_xor(p, 4);
            p += __shfl_xor(p, 8);
            if (n == 0) {
                float gv = gp[(size_t)l * 1024];
                yt[l][dl] = (p + uv[j] * Dv) * gv * sigmoidf_(gv);
            }
        }
    }
    __syncthreads();
    {
        int r = tid >> 2, q = tid & 3;
        *(float4*)(y + ((size_t)(b * LQ + l0 + r)) * DI + dt4 * 16 + q * 4) =
            *(const float4*)&yt[r][q * 4];
    }
}

// ---------------- head
__global__ __launch_bounds__(256) void k_head(const float* __restrict__ h,
                                              const float* __restrict__ Wa,
                                              const float* __restrict__ ba,
                                              const float* __restrict__ Wp,
                                              const float* __restrict__ bp,
                                              float* __restrict__ out) {
    int row = blockIdx.x * 4 + (threadIdx.x >> 6);
    int lane = threadIdx.x & 63;
    float4 v = ((const float4*)(h + (size_t)row * DM))[lane];
    float4 wa = ((const float4*)Wa)[lane];
    float4 wp = ((const float4*)Wp)[lane];
    float sa = v.x * wa.x + v.y * wa.y + v.z * wa.z + v.w * wa.w;
    float sph = v.x * wp.x + v.y * wp.y + v.z * wp.z + v.w * wp.w;
#pragma unroll
    for (int off = 32; off; off >>= 1) {
        sa += __shfl_xor(sa, off);
        sph += __shfl_xor(sph, off);
    }
    if (lane == 0) {
        out[(size_t)row * 2 + 0] = sa + ba[0];
        out[(size_t)row * 2 + 1] = tanhf(sph + bp[0]);
    }
}

extern "C" void kernel_launch(void* const* d_in, const int* in_sizes, int n_in,
                              void* d_out, int out_size, void* d_ws, size_t ws_size,
                              hipStream_t stream) {
    const float* x = (const float*)d_in[0];
    const float* pos = (const float*)d_in[1];
    const float* We = (const float*)d_in[2];
    const float* be = (const float*)d_in[3];
    const float* ln_w = (const float*)d_in[4];
    const float* W_in = (const float*)d_in[5];
    const float* conv_w = (const float*)d_in[6];
    const float* conv_b = (const float*)d_in[7];
    const float* W_x = (const float*)d_in[8];
    const float* W_dt = (const float*)d_in[9];
    const float* b_dt = (const float*)d_in[10];
    const float* A_log = (const float*)d_in[11];
    const float* D_skip = (const float*)d_in[12];
    const float* W_out = (const float*)d_in[13];
    const float* Wa = (const float*)d_in[14];
    const float* ba = (const float*)d_in[15];
    const float* Wp = (const float*)d_in[16];
    const float* bp = (const float*)d_in[17];

    float* ws = (float*)d_ws;
    float* h = ws;                        // 1,048,576
    float* xny = h + 1048576;             // 2,097,152 (xn aliases; y reuses)
    float* xg = xny + 2097152;            // 4,194,304
    float* hs = xg + 4194304;             // 2,097,152
    float* hsT = hs + 2097152;            // 2,097,152
    float* deltaT = hsT + 2097152;        // 2,097,152
    float* sp = deltaT + 2097152;         // 196,608
    float2* PS = (float2*)(sp + 196608);  // 524,288 float2
    float* hin = sp + 196608 + 1048576;   // 524,288
    float* xn = xny;
    float* y = xny;

    k_embed<<<4096, 256, 0, stream>>>(x, pos, We, be, h);
    for (int i = 0; i < NL; i++) {
        k_rmsnorm<<<1024, 256, 0, stream>>>(h, ln_w + i * DM, xn);
        dim3 g1(1024 / 64, 4096 / 64);
        k_gemm64<0><<<g1, 256, 0, stream>>>(xn, W_in + (size_t)i * DM * 2 * DI, nullptr, xg,
                                            4096, 1024, 256);
        k_convT<<<dim3(32, 8, 4), 256, 0, stream>>>(xg, conv_w + i * DI * KC, conv_b + i * DI,
                                                    hs, hsT);
        k_sp<<<768, 256, 0, stream>>>(hs, W_x + (size_t)i * DI * 48, sp);
        k_deltaT<<<8192, 256, 0, stream>>>(sp, W_dt + i * DTR * DI, b_dt + i * DI, deltaT);
        k_scanA<<<dim3(16, 32, 4), 256, 0, stream>>>(deltaT, hsT, sp, A_log + i * DI * NS, PS);
        k_scanB<<<128, 256, 0, stream>>>(PS, hin);
        k_scanC<<<dim3(16, 32, 4), 256, 0, stream>>>(deltaT, hsT, sp, xg, hin,
                                                     A_log + i * DI * NS, D_skip + i * DI, y);
        dim3 g4(256 / 64, 4096 / 64);
        k_gemm64<1><<<g4, 256, 0, stream>>>(y, W_out + (size_t)i * DI * DM, h, h,
                                            4096, 256, 512);
    }
    k_head<<<1024, 256, 0, stream>>>(h, Wa, ba, Wp, bp, (float*)d_out);
}

// Round 3
// 1086.180 us; speedup vs baseline: 7.0296x; 1.3551x over previous
//
#include <hip/hip_runtime.h>
#include <math.h>

#define BQ 4
#define LQ 1024
#define DM 256
#define DI 512
#define NS 16
#define DTR 16
#define KC 4
#define NL 8

typedef __bf16 bf16;
typedef __bf16 bf16x4 __attribute__((ext_vector_type(4)));
typedef __bf16 bf16x8 __attribute__((ext_vector_type(8)));
typedef float f32x4 __attribute__((ext_vector_type(4)));

static __device__ __forceinline__ float sigmoidf_(float x) { return 1.0f / (1.0f + expf(-x)); }
static __device__ __forceinline__ float siluf_(float x) { return x * sigmoidf_(x); }
static __device__ __forceinline__ float softplusf_(float x) {
    return fmaxf(x, 0.0f) + log1pf(expf(-fabsf(x)));
}
static __device__ __forceinline__ void cvt_hilo(float x, bf16& hi, bf16& lo) {
    hi = (bf16)x;
    lo = (bf16)(x - (float)hi);
}

// ---------------- embed
__global__ void k_embed(const float* __restrict__ x, const float* __restrict__ pos,
                        const float* __restrict__ We, const float* __restrict__ be,
                        float* __restrict__ h) {
    int idx = blockIdx.x * 256 + threadIdx.x;
    int d = idx % DM;
    int l = (idx / DM) % LQ;
    int b = idx / (DM * LQ);
    float v;
    if (d < 128) {
        float x0 = x[(b * LQ + l) * 2 + 0];
        float x1 = x[(b * LQ + l) * 2 + 1];
        v = fmaf(x0, We[d], fmaf(x1, We[128 + d], be[d]));
    } else {
        v = pos[l * 128 + (d - 128)];
    }
    h[idx] = v;
}

// ---------------- weight transpose + hi/lo bf16 convert: W[lay][K][N] -> WT[lay][N][K]
__global__ __launch_bounds__(256) void k_wt(const float* __restrict__ W, bf16* __restrict__ Th,
                                            bf16* __restrict__ Tl, int K, int N) {
    int k0 = blockIdx.x * 32, n0 = blockIdx.y * 32, lay = blockIdx.z;
    __shared__ float ts[32][36];
    int r = threadIdx.x >> 3, q = threadIdx.x & 7;
    float4 v = *(const float4*)(W + ((size_t)lay * K + k0 + r) * N + n0 + q * 4);
    *(float4*)&ts[r][q * 4] = v;
    __syncthreads();
    bf16x4 hv, lv;
#pragma unroll
    for (int i = 0; i < 4; i++) {
        bf16 hb, lb;
        cvt_hilo(ts[q * 4 + i][r], hb, lb);
        hv[i] = hb; lv[i] = lb;
    }
    size_t o = ((size_t)lay * N + n0 + r) * K + k0 + q * 4;
    *(bf16x4*)(Th + o) = hv;
    *(bf16x4*)(Tl + o) = lv;
}

// ---------------- rmsnorm -> hi/lo bf16
__global__ __launch_bounds__(256) void k_rmsnorm(const float* __restrict__ h,
                                                 const float* __restrict__ w,
                                                 bf16* __restrict__ xh, bf16* __restrict__ xl) {
    int row = blockIdx.x * 4 + (threadIdx.x >> 6);
    int lane = threadIdx.x & 63;
    float4 v = ((const float4*)(h + (size_t)row * DM))[lane];
    float ss = v.x * v.x + v.y * v.y + v.z * v.z + v.w * v.w;
#pragma unroll
    for (int off = 32; off; off >>= 1) ss += __shfl_xor(ss, off);
    float scale = 1.0f / sqrtf(ss * (1.0f / DM) + 1e-5f);
    float4 wv = ((const float4*)w)[lane];
    float o[4] = {v.x * scale * wv.x, v.y * scale * wv.y, v.z * scale * wv.z,
                  v.w * scale * wv.w};
    bf16x4 hv, lv;
#pragma unroll
    for (int i = 0; i < 4; i++) {
        bf16 hb, lb;
        cvt_hilo(o[i], hb, lb);
        hv[i] = hb; lv[i] = lb;
    }
    *(bf16x4*)(xh + (size_t)row * DM + lane * 4) = hv;
    *(bf16x4*)(xl + (size_t)row * DM + lane * 4) = lv;
}

// ---------------- split-bf16 (3-term) MFMA GEMM: C = A(MxK) @ B^T(NxK)^T [+Res]
// A hi/lo: [M][K] bf16 ; B hi/lo: [N][K] bf16 (transposed weights)
template <int RES>
__global__ __launch_bounds__(256) void k_gemm_bf3(const bf16* __restrict__ Ah,
                                                  const bf16* __restrict__ Al,
                                                  const bf16* __restrict__ Bh,
                                                  const bf16* __restrict__ Bl,
                                                  const float* __restrict__ Res,
                                                  float* __restrict__ C, int M, int N, int K) {
    __shared__ __align__(16) bf16 sA[2][2][64 * 32];
    __shared__ __align__(16) bf16 sB[2][2][64 * 32];
    const int tid = threadIdx.x;
    const int lane = tid & 63, wave = tid >> 6;
    const int wr = wave >> 1, wc = wave & 1;
    const int bm = blockIdx.y * 64, bn = blockIdx.x * 64;
    // staging: thread -> one 16B chunk per plane
    const int srow = tid >> 2, sgrp = tid & 3;
    const int ldst = srow * 32 + ((sgrp ^ (srow & 3)) * 8);
    const size_t aoff = (size_t)(bm + srow) * K + sgrp * 8;
    const size_t boff = (size_t)(bn + srow) * K + sgrp * 8;
    // frag read offsets
    const int r15 = lane & 15, g = lane >> 4;
    const int arow0 = wr * 32 + r15;
    const int aoffs0 = arow0 * 32 + ((g ^ (arow0 & 3)) * 8);
    const int aoffs1 = aoffs0 + 16 * 32;
    const int bcol0 = wc * 32 + r15;
    const int boffs0 = bcol0 * 32 + ((g ^ (bcol0 & 3)) * 8);
    const int boffs1 = boffs0 + 16 * 32;
    f32x4 acc[2][2] = {};
    const int nt = K >> 5;
    uint4 rAh = *(const uint4*)(Ah + aoff);
    uint4 rAl = *(const uint4*)(Al + aoff);
    uint4 rBh = *(const uint4*)(Bh + boff);
    uint4 rBl = *(const uint4*)(Bl + boff);
    *(uint4*)&sA[0][0][ldst] = rAh;
    *(uint4*)&sA[0][1][ldst] = rAl;
    *(uint4*)&sB[0][0][ldst] = rBh;
    *(uint4*)&sB[0][1][ldst] = rBl;
    __syncthreads();
    int cur = 0;
    for (int t = 0; t < nt; ++t) {
        if (t + 1 < nt) {
            size_t ko = (size_t)(t + 1) * 32;
            rAh = *(const uint4*)(Ah + aoff + ko);
            rAl = *(const uint4*)(Al + aoff + ko);
            rBh = *(const uint4*)(Bh + boff + ko);
            rBl = *(const uint4*)(Bl + boff + ko);
        }
        bf16x8 a0h = *(const bf16x8*)&sA[cur][0][aoffs0];
        bf16x8 a1h = *(const bf16x8*)&sA[cur][0][aoffs1];
        bf16x8 a0l = *(const bf16x8*)&sA[cur][1][aoffs0];
        bf16x8 a1l = *(const bf16x8*)&sA[cur][1][aoffs1];
        bf16x8 b0h = *(const bf16x8*)&sB[cur][0][boffs0];
        bf16x8 b1h = *(const bf16x8*)&sB[cur][0][boffs1];
        bf16x8 b0l = *(const bf16x8*)&sB[cur][1][boffs0];
        bf16x8 b1l = *(const bf16x8*)&sB[cur][1][boffs1];
        acc[0][0] = __builtin_amdgcn_mfma_f32_16x16x32_bf16(a0h, b0h, acc[0][0], 0, 0, 0);
        acc[0][1] = __builtin_amdgcn_mfma_f32_16x16x32_bf16(a0h, b1h, acc[0][1], 0, 0, 0);
        acc[1][0] = __builtin_amdgcn_mfma_f32_16x16x32_bf16(a1h, b0h, acc[1][0], 0, 0, 0);
        acc[1][1] = __builtin_amdgcn_mfma_f32_16x16x32_bf16(a1h, b1h, acc[1][1], 0, 0, 0);
        acc[0][0] = __builtin_amdgcn_mfma_f32_16x16x32_bf16(a0h, b0l, acc[0][0], 0, 0, 0);
        acc[0][1] = __builtin_amdgcn_mfma_f32_16x16x32_bf16(a0h, b1l, acc[0][1], 0, 0, 0);
        acc[1][0] = __builtin_amdgcn_mfma_f32_16x16x32_bf16(a1h, b0l, acc[1][0], 0, 0, 0);
        acc[1][1] = __builtin_amdgcn_mfma_f32_16x16x32_bf16(a1h, b1l, acc[1][1], 0, 0, 0);
        acc[0][0] = __builtin_amdgcn_mfma_f32_16x16x32_bf16(a0l, b0h, acc[0][0], 0, 0, 0);
        acc[0][1] = __builtin_amdgcn_mfma_f32_16x16x32_bf16(a0l, b1h, acc[0][1], 0, 0, 0);
        acc[1][0] = __builtin_amdgcn_mfma_f32_16x16x32_bf16(a1l, b0h, acc[1][0], 0, 0, 0);
        acc[1][1] = __builtin_amdgcn_mfma_f32_16x16x32_bf16(a1l, b1h, acc[1][1], 0, 0, 0);
        if (t + 1 < nt) {
            int nb = cur ^ 1;
            *(uint4*)&sA[nb][0][ldst] = rAh;
            *(uint4*)&sA[nb][1][ldst] = rAl;
            *(uint4*)&sB[nb][0][ldst] = rBh;
            *(uint4*)&sB[nb][1][ldst] = rBl;
        }
        __syncthreads();
        cur ^= 1;
    }
#pragma unroll
    for (int i = 0; i < 2; i++)
#pragma unroll
        for (int j = 0; j < 2; j++) {
            int row0 = bm + wr * 32 + i * 16 + g * 4;
            int col = bn + wc * 32 + j * 16 + r15;
#pragma unroll
            for (int r = 0; r < 4; r++) {
                size_t o = (size_t)(row0 + r) * N + col;
                float v = acc[i][j][r];
                if (RES) v += Res[o];
                C[o] = v;
            }
        }
}

// ---------------- tiled transpose + causal depthwise conv (K=4) + SiLU
__global__ __launch_bounds__(256) void k_convT(const float* __restrict__ xg,
                                               const float* __restrict__ cw,
                                               const float* __restrict__ cb,
                                               float* __restrict__ hs,
                                               float* __restrict__ hsT) {
    int l0 = blockIdx.x * 32, d0 = blockIdx.y * 64, b = blockIdx.z;
    __shared__ float xs[35][68];
    __shared__ float cs[32][68];
    int tid = threadIdx.x;
    for (int idx = tid; idx < 35 * 16; idx += 256) {
        int r = idx >> 4, q = idx & 15;
        int l = l0 - 3 + r;
        float4 v = {0.f, 0.f, 0.f, 0.f};
        if (l >= 0) v = *(const float4*)(xg + ((size_t)(b * LQ + l)) * 1024 + d0 + q * 4);
        *(float4*)&xs[r][q * 4] = v;
    }
    __syncthreads();
    int dl = tid >> 2, lq = tid & 3;
    const float* w = cw + (d0 + dl) * KC;
    float w0 = w[0], w1 = w[1], w2 = w[2], w3 = w[3];
    float bb = cb[d0 + dl];
    float out[8];
    float x0 = xs[lq * 8 + 0][dl];
    float x1 = xs[lq * 8 + 1][dl];
    float x2 = xs[lq * 8 + 2][dl];
#pragma unroll
    for (int j = 0; j < 8; ++j) {
        float x3 = xs[lq * 8 + 3 + j][dl];
        float v = fmaf(w0, x0, fmaf(w1, x1, fmaf(w2, x2, fmaf(w3, x3, bb))));
        out[j] = siluf_(v);
        x0 = x1; x1 = x2; x2 = x3;
    }
    size_t to = ((size_t)(b * DI + d0 + dl)) * LQ + l0 + lq * 8;
    float4 o0 = {out[0], out[1], out[2], out[3]};
    float4 o1 = {out[4], out[5], out[6], out[7]};
    *(float4*)(hsT + to) = o0;
    *(float4*)(hsT + to + 4) = o1;
#pragma unroll
    for (int j = 0; j < 8; ++j) cs[lq * 8 + j][dl] = out[j];
    __syncthreads();
    for (int idx = tid; idx < 32 * 16; idx += 256) {
        int r = idx >> 4, q = idx & 15;
        *(float4*)(hs + ((size_t)(b * LQ + l0 + r)) * DI + d0 + q * 4) =
            *(const float4*)&cs[r][q * 4];
    }
}

// ---------------- sp = hs(4096x512) @ W_x(512x48)
__global__ void k_sp(const float* __restrict__ hs, const float* __restrict__ Wx,
                     float* __restrict__ sp) {
    int idx = blockIdx.x * 256 + threadIdx.x;
    int j = idx % 48;
    int row = idx / 48;
    const float* a = hs + (size_t)row * DI;
    float acc = 0.f;
#pragma unroll 8
    for (int k = 0; k < DI; k++) acc = fmaf(a[k], Wx[k * 48 + j], acc);
    sp[idx] = acc;
}

// ---------------- deltaT[b,d,l] = softplus(dt(row) @ W_dt + b_dt)
__global__ void k_deltaT(const float* __restrict__ sp, const float* __restrict__ Wdt,
                         const float* __restrict__ bdt, float* __restrict__ deltaT) {
    int idx = blockIdx.x * 256 + threadIdx.x;
    int l = idx & 1023;
    int d = (idx >> 10) & 511;
    int b = idx >> 19;
    const float4* dt4 = (const float4*)(sp + ((size_t)(b * LQ + l)) * 48);
    float4 t0 = dt4[0], t1 = dt4[1], t2 = dt4[2], t3 = dt4[3];
    float acc = bdt[d];
    acc = fmaf(t0.x, Wdt[0 * DI + d], acc);
    acc = fmaf(t0.y, Wdt[1 * DI + d], acc);
    acc = fmaf(t0.z, Wdt[2 * DI + d], acc);
    acc = fmaf(t0.w, Wdt[3 * DI + d], acc);
    acc = fmaf(t1.x, Wdt[4 * DI + d], acc);
    acc = fmaf(t1.y, Wdt[5 * DI + d], acc);
    acc = fmaf(t1.z, Wdt[6 * DI + d], acc);
    acc = fmaf(t1.w, Wdt[7 * DI + d], acc);
    acc = fmaf(t2.x, Wdt[8 * DI + d], acc);
    acc = fmaf(t2.y, Wdt[9 * DI + d], acc);
    acc = fmaf(t2.z, Wdt[10 * DI + d], acc);
    acc = fmaf(t2.w, Wdt[11 * DI + d], acc);
    acc = fmaf(t3.x, Wdt[12 * DI + d], acc);
    acc = fmaf(t3.y, Wdt[13 * DI + d], acc);
    acc = fmaf(t3.z, Wdt[14 * DI + d], acc);
    acc = fmaf(t3.w, Wdt[15 * DI + d], acc);
    deltaT[idx] = softplusf_(acc);
}

// ---------------- scan phase A: 16 states per thread, chunk of 16 l
__global__ __launch_bounds__(256) void k_scanA(const float* __restrict__ deltaT,
                                               const float* __restrict__ hsT,
                                               const float* __restrict__ sp,
                                               const float* __restrict__ Alog,
                                               float* __restrict__ PS) {
    int c = blockIdx.x, b = blockIdx.z;
    int dl = threadIdx.x;
    int d = blockIdx.y * 256 + dl;
    __shared__ float Bs[16][16];
    {
        int l = threadIdx.x >> 4, n = threadIdx.x & 15;
        Bs[l][n] = sp[((size_t)(b * LQ + c * 16 + l)) * 48 + DTR + n];
    }
    float Av[16];
    {
        const float4* ap = (const float4*)(Alog + (size_t)d * 16);
#pragma unroll
        for (int i = 0; i < 4; i++) {
            float4 v = ap[i];
            Av[4 * i + 0] = -expf(v.x);
            Av[4 * i + 1] = -expf(v.y);
            Av[4 * i + 2] = -expf(v.z);
            Av[4 * i + 3] = -expf(v.w);
        }
    }
    float dv[16], uv[16];
    {
        const float4* dp = (const float4*)(deltaT + ((size_t)(b * DI + d)) * LQ + c * 16);
        const float4* up = (const float4*)(hsT + ((size_t)(b * DI + d)) * LQ + c * 16);
#pragma unroll
        for (int i = 0; i < 4; i++) {
            float4 a = dp[i], u = up[i];
            dv[4 * i] = a.x; dv[4 * i + 1] = a.y; dv[4 * i + 2] = a.z; dv[4 * i + 3] = a.w;
            uv[4 * i] = u.x; uv[4 * i + 1] = u.y; uv[4 * i + 2] = u.z; uv[4 * i + 3] = u.w;
        }
    }
    __syncthreads();
    float hst[16], P[16];
#pragma unroll
    for (int n = 0; n < 16; n++) { hst[n] = 0.f; P[n] = 1.f; }
#pragma unroll
    for (int l = 0; l < 16; l++) {
        float t = dv[l] * uv[l];
#pragma unroll
        for (int n = 0; n < 16; n++) {
            float dA = __expf(dv[l] * Av[n]);
            hst[n] = fmaf(dA, hst[n], t * Bs[l][n]);
            P[n] *= dA;
        }
    }
    float* pb = PS + ((size_t)((b * 64 + c) * DI + d)) * 32;
#pragma unroll
    for (int i = 0; i < 8; i++) {
        float4 o = {P[2 * i], hst[2 * i], P[2 * i + 1], hst[2 * i + 1]};
        ((float4*)pb)[i] = o;
    }
}

// ---------------- scan phase B: serial combine over 64 chunks; hin written into P slot
__global__ void k_scanB(float* __restrict__ PS) {
    int idx = blockIdx.x * 256 + threadIdx.x;  // 32768 = b*8192 + d*16 + n
    int b = idx >> 13, rest = idx & 8191;
    float h = 0.f;
#pragma unroll 4
    for (int c = 0; c < 64; c++) {
        size_t o = ((size_t)(b * 64 + c)) * 8192 + rest;
        float2 ps = ((const float2*)PS)[o];
        PS[o * 2] = h;  // overwrite P with incoming state
        h = fmaf(ps.x, h, ps.y);
    }
}

// ---------------- scan phase C: replay chunk from hin, emit y as bf16 hi/lo
__global__ __launch_bounds__(256) void k_scanC(const float* __restrict__ deltaT,
                                               const float* __restrict__ hsT,
                                               const float* __restrict__ sp,
                                               const float* __restrict__ xg,
                                               const float* __restrict__ PS,
                                               const float* __restrict__ Alog,
                                               const float* __restrict__ Dsk,
                                               bf16* __restrict__ yh, bf16* __restrict__ yl) {
    int c = blockIdx.x, b = blockIdx.z;
    int dl = threadIdx.x;
    int d0 = blockIdx.y * 256;
    int d = d0 + dl;
    __shared__ float BCs[16][32];
    __shared__ float G[16 * 256];
    for (int f = threadIdx.x; f < 512; f += 256) {
        int l = f >> 5, j = f & 31;
        BCs[l][j] = sp[((size_t)(b * LQ + c * 16 + l)) * 48 + DTR + j];
    }
#pragma unroll
    for (int it = 0; it < 4; ++it) {
        int f = threadIdx.x + it * 256;
        int l = f >> 6, q = f & 63;
        float4 v = *(const float4*)(xg + ((size_t)(b * LQ + c * 16 + l)) * 1024 + DI + d0 + q * 4);
        *(float4*)&G[l * 256 + q * 4] = v;
    }
    float Av[16];
    {
        const float4* ap = (const float4*)(Alog + (size_t)d * 16);
#pragma unroll
        for (int i = 0; i < 4; i++) {
            float4 v = ap[i];
            Av[4 * i + 0] = -expf(v.x);
            Av[4 * i + 1] = -expf(v.y);
            Av[4 * i + 2] = -expf(v.z);
            Av[4 * i + 3] = -expf(v.w);
        }
    }
    float Dv = Dsk[d];
    float hst[16];
    {
        const float4* pp = (const float4*)(PS + ((size_t)((b * 64 + c) * DI + d)) * 32);
#pragma unroll
        for (int i = 0; i < 8; i++) {
            float4 v = pp[i];
            hst[2 * i] = v.x;
            hst[2 * i + 1] = v.z;
        }
    }
    float dv[16], uv[16];
    {
        const float4* dp = (const float4*)(deltaT + ((size_t)(b * DI + d)) * LQ + c * 16);
        const float4* up = (const float4*)(hsT + ((size_t)(b * DI + d)) * LQ + c * 16);
#pragma unroll
        for (int i = 0; i < 4; i++) {
            float4 a = dp[i], u = up[i];
            dv[4 * i] = a.x; dv[4 * i + 1] = a.y; dv[4 * i + 2] = a.z; dv[4 * i + 3] = a.w;
            uv[4 * i] = u.x; uv[4 * i + 1] = u.y; uv[4 * i + 2] = u.z; uv[4 * i + 3] = u.w;
        }
    }
    __syncthreads();
#pragma unroll
    for (int l = 0; l < 16; l++) {
        float t = dv[l] * uv[l];
        float p0 = 0.f, p1 = 0.f;
#pragma unroll
        for (int n = 0; n < 16; n += 2) {
            float dA0 = __expf(dv[l] * Av[n]);
            hst[n] = fmaf(dA0, hst[n], t * BCs[l][n]);
            p0 = fmaf(hst[n], BCs[l][16 + n], p0);
            float dA1 = __expf(dv[l] * Av[n + 1]);
            hst[n + 1] = fmaf(dA1, hst[n + 1], t * BCs[l][n + 1]);
            p1 = fmaf(hst[n + 1], BCs[l][16 + n + 1], p1);
        }
        float gv = G[l * 256 + dl];
        G[l * 256 + dl] = (p0 + p1 + uv[l] * Dv) * gv * sigmoidf_(gv);
    }
    __syncthreads();
#pragma unroll
    for (int it = 0; it < 4; ++it) {
        int f = threadIdx.x + it * 256;
        int l = f >> 6, q = f & 63;
        float4 v = *(const float4*)&G[l * 256 + q * 4];
        bf16x4 hv, lv;
        bf16 hb, lb;
        cvt_hilo(v.x, hb, lb); hv[0] = hb; lv[0] = lb;
        cvt_hilo(v.y, hb, lb); hv[1] = hb; lv[1] = lb;
        cvt_hilo(v.z, hb, lb); hv[2] = hb; lv[2] = lb;
        cvt_hilo(v.w, hb, lb); hv[3] = hb; lv[3] = lb;
        size_t o = ((size_t)(b * LQ + c * 16 + l)) * DI + d0 + q * 4;
        *(bf16x4*)(yh + o) = hv;
        *(bf16x4*)(yl + o) = lv;
    }
}

// ---------------- head
__global__ __launch_bounds__(256) void k_head(const float* __restrict__ h,
                                              const float* __restrict__ Wa,
                                              const float* __restrict__ ba,
                                              const float* __restrict__ Wp,
                                              const float* __restrict__ bp,
                                              float* __restrict__ out) {
    int row = blockIdx.x * 4 + (threadIdx.x >> 6);
    int lane = threadIdx.x & 63;
    float4 v = ((const float4*)(h + (size_t)row * DM))[lane];
    float4 wa = ((const float4*)Wa)[lane];
    float4 wp = ((const float4*)Wp)[lane];
    float sa = v.x * wa.x + v.y * wa.y + v.z * wa.z + v.w * wa.w;
    float sph = v.x * wp.x + v.y * wp.y + v.z * wp.z + v.w * wp.w;
#pragma unroll
    for (int off = 32; off; off >>= 1) {
        sa += __shfl_xor(sa, off);
        sph += __shfl_xor(sph, off);
    }
    if (lane == 0) {
        out[(size_t)row * 2 + 0] = sa + ba[0];
        out[(size_t)row * 2 + 1] = tanhf(sph + bp[0]);
    }
}

extern "C" void kernel_launch(void* const* d_in, const int* in_sizes, int n_in,
                              void* d_out, int out_size, void* d_ws, size_t ws_size,
                              hipStream_t stream) {
    const float* x = (const float*)d_in[0];
    const float* pos = (const float*)d_in[1];
    const float* We = (const float*)d_in[2];
    const float* be = (const float*)d_in[3];
    const float* ln_w = (const float*)d_in[4];
    const float* W_in = (const float*)d_in[5];
    const float* conv_w = (const float*)d_in[6];
    const float* conv_b = (const float*)d_in[7];
    const float* W_x = (const float*)d_in[8];
    const float* W_dt = (const float*)d_in[9];
    const float* b_dt = (const float*)d_in[10];
    const float* A_log = (const float*)d_in[11];
    const float* D_skip = (const float*)d_in[12];
    const float* W_out = (const float*)d_in[13];
    const float* Wa = (const float*)d_in[14];
    const float* ba = (const float*)d_in[15];
    const float* Wp = (const float*)d_in[16];
    const float* bp = (const float*)d_in[17];

    float* ws = (float*)d_ws;
    float* h = ws;                       // 1,048,576 f
    float* xg = h + 1048576;             // 4,194,304 f
    float* hs = xg + 4194304;            // 2,097,152 f
    float* hsT = hs + 2097152;           // 2,097,152 f
    float* deltaT = hsT + 2097152;       // 2,097,152 f
    float* sp = deltaT + 2097152;        // 196,608 f
    float* PS = sp + 196608;             // 4,194,304 f (float2 pairs)
    bf16* xn_hi = (bf16*)(PS + 4194304); // 1,048,576 bf16
    bf16* xn_lo = xn_hi + 1048576;
    bf16* y_hi = xn_lo + 1048576;        // 2,097,152 bf16
    bf16* y_lo = y_hi + 2097152;
    bf16* wtin_h = y_lo + 2097152;       // 2,097,152 bf16
    bf16* wtin_l = wtin_h + 2097152;
    bf16* wtout_h = wtin_l + 2097152;    // 1,048,576 bf16
    bf16* wtout_l = wtout_h + 1048576;

    k_wt<<<dim3(8, 32, 8), 256, 0, stream>>>(W_in, wtin_h, wtin_l, 256, 1024);
    k_wt<<<dim3(16, 8, 8), 256, 0, stream>>>(W_out, wtout_h, wtout_l, 512, 256);
    k_embed<<<4096, 256, 0, stream>>>(x, pos, We, be, h);
    for (int i = 0; i < NL; i++) {
        k_rmsnorm<<<1024, 256, 0, stream>>>(h, ln_w + i * DM, xn_hi, xn_lo);
        k_gemm_bf3<0><<<dim3(16, 64), 256, 0, stream>>>(
            xn_hi, xn_lo, wtin_h + (size_t)i * 1024 * 256, wtin_l + (size_t)i * 1024 * 256,
            nullptr, xg, 4096, 1024, 256);
        k_convT<<<dim3(32, 8, 4), 256, 0, stream>>>(xg, conv_w + i * DI * KC, conv_b + i * DI,
                                                    hs, hsT);
        k_sp<<<768, 256, 0, stream>>>(hs, W_x + (size_t)i * DI * 48, sp);
        k_deltaT<<<8192, 256, 0, stream>>>(sp, W_dt + i * DTR * DI, b_dt + i * DI, deltaT);
        k_scanA<<<dim3(64, 2, 4), 256, 0, stream>>>(deltaT, hsT, sp, A_log + i * DI * NS, PS);
        k_scanB<<<128, 256, 0, stream>>>(PS);
        k_scanC<<<dim3(64, 2, 4), 256, 0, stream>>>(deltaT, hsT, sp, xg, PS,
                                                    A_log + i * DI * NS, D_skip + i * DI,
                                                    y_hi, y_lo);
        k_gemm_bf3<1><<<dim3(4, 64), 256, 0, stream>>>(
            y_hi, y_lo, wtout_h + (size_t)i * 256 * 512, wtout_l + (size_t)i * 256 * 512,
            h, h, 4096, 256, 512);
    }
    k_head<<<1024, 256, 0, stream>>>(h, Wa, ba, Wp, bp, (float*)d_out);
}

// Round 4
// 833.892 us; speedup vs baseline: 9.1564x; 1.3025x over previous
//
#include <hip/hip_runtime.h>
#include <math.h>

#define BQ 4
#define LQ 1024
#define DM 256
#define DI 512
#define NS 16
#define DTR 16
#define KC 4
#define NL 8

typedef __bf16 bf16;
typedef __bf16 bf16x4 __attribute__((ext_vector_type(4)));
typedef __bf16 bf16x8 __attribute__((ext_vector_type(8)));
typedef float f32x4 __attribute__((ext_vector_type(4)));

static __device__ __forceinline__ float sigmoidf_(float x) { return 1.0f / (1.0f + expf(-x)); }
static __device__ __forceinline__ float siluf_(float x) { return x * sigmoidf_(x); }
static __device__ __forceinline__ float softplusf_(float x) {
    return fmaxf(x, 0.0f) + log1pf(expf(-fabsf(x)));
}
static __device__ __forceinline__ void cvt_hilo(float x, bf16& hi, bf16& lo) {
    hi = (bf16)x;
    lo = (bf16)(x - (float)hi);
}

// ---------------- embed
__global__ void k_embed(const float* __restrict__ x, const float* __restrict__ pos,
                        const float* __restrict__ We, const float* __restrict__ be,
                        float* __restrict__ h) {
    int idx = blockIdx.x * 256 + threadIdx.x;
    int d = idx % DM;
    int l = (idx / DM) % LQ;
    int b = idx / (DM * LQ);
    float v;
    if (d < 128) {
        float x0 = x[(b * LQ + l) * 2 + 0];
        float x1 = x[(b * LQ + l) * 2 + 1];
        v = fmaf(x0, We[d], fmaf(x1, We[128 + d], be[d]));
    } else {
        v = pos[l * 128 + (d - 128)];
    }
    h[idx] = v;
}

// ---------------- zero sp
__global__ void k_zero(float* __restrict__ p) {
    int i = (blockIdx.x * 256 + threadIdx.x) * 4;
    float4 z = {0.f, 0.f, 0.f, 0.f};
    *(float4*)(p + i) = z;
}

// ---------------- weight transpose + hi/lo bf16 convert: W[lay][K][N] -> WT[lay][N][K]
__global__ __launch_bounds__(256) void k_wt(const float* __restrict__ W, bf16* __restrict__ Th,
                                            bf16* __restrict__ Tl, int K, int N) {
    int k0 = blockIdx.x * 32, n0 = blockIdx.y * 32, lay = blockIdx.z;
    __shared__ float ts[32][36];
    int r = threadIdx.x >> 3, q = threadIdx.x & 7;
    float4 v = *(const float4*)(W + ((size_t)lay * K + k0 + r) * N + n0 + q * 4);
    *(float4*)&ts[r][q * 4] = v;
    __syncthreads();
    bf16x4 hv, lv;
#pragma unroll
    for (int i = 0; i < 4; i++) {
        bf16 hb, lb;
        cvt_hilo(ts[q * 4 + i][r], hb, lb);
        hv[i] = hb; lv[i] = lb;
    }
    size_t o = ((size_t)lay * N + n0 + r) * K + k0 + q * 4;
    *(bf16x4*)(Th + o) = hv;
    *(bf16x4*)(Tl + o) = lv;
}

// ---------------- rmsnorm -> hi/lo bf16
__global__ __launch_bounds__(256) void k_rmsnorm(const float* __restrict__ h,
                                                 const float* __restrict__ w,
                                                 bf16* __restrict__ xh, bf16* __restrict__ xl) {
    int row = blockIdx.x * 4 + (threadIdx.x >> 6);
    int lane = threadIdx.x & 63;
    float4 v = ((const float4*)(h + (size_t)row * DM))[lane];
    float ss = v.x * v.x + v.y * v.y + v.z * v.z + v.w * v.w;
#pragma unroll
    for (int off = 32; off; off >>= 1) ss += __shfl_xor(ss, off);
    float scale = 1.0f / sqrtf(ss * (1.0f / DM) + 1e-5f);
    float4 wv = ((const float4*)w)[lane];
    float o[4] = {v.x * scale * wv.x, v.y * scale * wv.y, v.z * scale * wv.z,
                  v.w * scale * wv.w};
    bf16x4 hv, lv;
#pragma unroll
    for (int i = 0; i < 4; i++) {
        bf16 hb, lb;
        cvt_hilo(o[i], hb, lb);
        hv[i] = hb; lv[i] = lb;
    }
    *(bf16x4*)(xh + (size_t)row * DM + lane * 4) = hv;
    *(bf16x4*)(xl + (size_t)row * DM + lane * 4) = lv;
}

// ---------------- split-bf16 (3-term) MFMA GEMM, 64x64 tile, BK=64, dbuf LDS
template <int RES>
__global__ __launch_bounds__(256) void k_gemm_bf3(const bf16* __restrict__ Ah,
                                                  const bf16* __restrict__ Al,
                                                  const bf16* __restrict__ Bh,
                                                  const bf16* __restrict__ Bl,
                                                  const float* __restrict__ Res,
                                                  float* __restrict__ C, int M, int N, int K) {
    __shared__ __align__(16) bf16 sA[2][2][64 * 64];
    __shared__ __align__(16) bf16 sB[2][2][64 * 64];
    const int tid = threadIdx.x;
    const int lane = tid & 63, wave = tid >> 6;
    const int wr = wave >> 1, wc = wave & 1;
    const int bm = blockIdx.y * 64, bn = blockIdx.x * 64;
    // staging: thread covers row=tid>>2, chunks c0,c0+1 (8 chunks of 8 bf16 per 64-k row)
    const int srow = tid >> 2;
    const int sc0 = (tid & 3) * 2;
    const int ssw = srow & 7;
    const int ld0 = srow * 64 + ((sc0) ^ ssw) * 8;
    const int ld1 = srow * 64 + ((sc0 + 1) ^ ssw) * 8;
    const size_t aoff = (size_t)(bm + srow) * K + sc0 * 8;
    const size_t boff = (size_t)(bn + srow) * K + sc0 * 8;
    // frag mapping: lane = r15 + 16*g, g in 0..3
    const int r15 = lane & 15, g = lane >> 4;
    const int arow0 = wr * 32 + r15;
    const int brow0 = wc * 32 + r15;
    const int asw = arow0 & 7;
    const int bsw = brow0 & 7;
    f32x4 acc[2][2] = {};
    const int nt = K >> 6;
    uint4 rA0h, rA1h, rA0l, rA1l, rB0h, rB1h, rB0l, rB1l;
    rA0h = *(const uint4*)(Ah + aoff);     rA1h = *(const uint4*)(Ah + aoff + 8);
    rA0l = *(const uint4*)(Al + aoff);     rA1l = *(const uint4*)(Al + aoff + 8);
    rB0h = *(const uint4*)(Bh + boff);     rB1h = *(const uint4*)(Bh + boff + 8);
    rB0l = *(const uint4*)(Bl + boff);     rB1l = *(const uint4*)(Bl + boff + 8);
    *(uint4*)&sA[0][0][ld0] = rA0h; *(uint4*)&sA[0][0][ld1] = rA1h;
    *(uint4*)&sA[0][1][ld0] = rA0l; *(uint4*)&sA[0][1][ld1] = rA1l;
    *(uint4*)&sB[0][0][ld0] = rB0h; *(uint4*)&sB[0][0][ld1] = rB1h;
    *(uint4*)&sB[0][1][ld0] = rB0l; *(uint4*)&sB[0][1][ld1] = rB1l;
    __syncthreads();
    int cur = 0;
    for (int t = 0; t < nt; ++t) {
        if (t + 1 < nt) {
            size_t ko = (size_t)(t + 1) * 64;
            rA0h = *(const uint4*)(Ah + aoff + ko);     rA1h = *(const uint4*)(Ah + aoff + ko + 8);
            rA0l = *(const uint4*)(Al + aoff + ko);     rA1l = *(const uint4*)(Al + aoff + ko + 8);
            rB0h = *(const uint4*)(Bh + boff + ko);     rB1h = *(const uint4*)(Bh + boff + ko + 8);
            rB0l = *(const uint4*)(Bl + boff + ko);     rB1l = *(const uint4*)(Bl + boff + ko + 8);
        }
#pragma unroll
        for (int kk = 0; kk < 2; ++kk) {
            const int ca = ((kk * 4 + g) ^ asw) * 8;
            const int cb = ((kk * 4 + g) ^ bsw) * 8;
            bf16x8 a0h = *(const bf16x8*)&sA[cur][0][arow0 * 64 + ca];
            bf16x8 a1h = *(const bf16x8*)&sA[cur][0][(arow0 + 16) * 64 + ca];
            bf16x8 a0l = *(const bf16x8*)&sA[cur][1][arow0 * 64 + ca];
            bf16x8 a1l = *(const bf16x8*)&sA[cur][1][(arow0 + 16) * 64 + ca];
            bf16x8 b0h = *(const bf16x8*)&sB[cur][0][brow0 * 64 + cb];
            bf16x8 b1h = *(const bf16x8*)&sB[cur][0][(brow0 + 16) * 64 + cb];
            bf16x8 b0l = *(const bf16x8*)&sB[cur][1][brow0 * 64 + cb];
            bf16x8 b1l = *(const bf16x8*)&sB[cur][1][(brow0 + 16) * 64 + cb];
            acc[0][0] = __builtin_amdgcn_mfma_f32_16x16x32_bf16(a0h, b0h, acc[0][0], 0, 0, 0);
            acc[0][1] = __builtin_amdgcn_mfma_f32_16x16x32_bf16(a0h, b1h, acc[0][1], 0, 0, 0);
            acc[1][0] = __builtin_amdgcn_mfma_f32_16x16x32_bf16(a1h, b0h, acc[1][0], 0, 0, 0);
            acc[1][1] = __builtin_amdgcn_mfma_f32_16x16x32_bf16(a1h, b1h, acc[1][1], 0, 0, 0);
            acc[0][0] = __builtin_amdgcn_mfma_f32_16x16x32_bf16(a0h, b0l, acc[0][0], 0, 0, 0);
            acc[0][1] = __builtin_amdgcn_mfma_f32_16x16x32_bf16(a0h, b1l, acc[0][1], 0, 0, 0);
            acc[1][0] = __builtin_amdgcn_mfma_f32_16x16x32_bf16(a1h, b0l, acc[1][0], 0, 0, 0);
            acc[1][1] = __builtin_amdgcn_mfma_f32_16x16x32_bf16(a1h, b1l, acc[1][1], 0, 0, 0);
            acc[0][0] = __builtin_amdgcn_mfma_f32_16x16x32_bf16(a0l, b0h, acc[0][0], 0, 0, 0);
            acc[0][1] = __builtin_amdgcn_mfma_f32_16x16x32_bf16(a0l, b1h, acc[0][1], 0, 0, 0);
            acc[1][0] = __builtin_amdgcn_mfma_f32_16x16x32_bf16(a1l, b0h, acc[1][0], 0, 0, 0);
            acc[1][1] = __builtin_amdgcn_mfma_f32_16x16x32_bf16(a1l, b1h, acc[1][1], 0, 0, 0);
        }
        if (t + 1 < nt) {
            int nb = cur ^ 1;
            *(uint4*)&sA[nb][0][ld0] = rA0h; *(uint4*)&sA[nb][0][ld1] = rA1h;
            *(uint4*)&sA[nb][1][ld0] = rA0l; *(uint4*)&sA[nb][1][ld1] = rA1l;
            *(uint4*)&sB[nb][0][ld0] = rB0h; *(uint4*)&sB[nb][0][ld1] = rB1h;
            *(uint4*)&sB[nb][1][ld0] = rB0l; *(uint4*)&sB[nb][1][ld1] = rB1l;
        }
        __syncthreads();
        cur ^= 1;
    }
#pragma unroll
    for (int i = 0; i < 2; i++)
#pragma unroll
        for (int j = 0; j < 2; j++) {
            int row0 = bm + wr * 32 + i * 16 + g * 4;
            int col = bn + wc * 32 + j * 16 + r15;
#pragma unroll
            for (int r = 0; r < 4; r++) {
                size_t o = (size_t)(row0 + r) * N + col;
                float v = acc[i][j][r];
                if (RES) v += Res[o];
                C[o] = v;
            }
        }
}

// ---------------- causal depthwise conv (K=4) + SiLU + fused sp split-K partials
// reads xg[b,l,0:512]; writes hs [b,l,d]; atomicAdd sp partials
__global__ __launch_bounds__(256) void k_conv_sp(const float* __restrict__ xg,
                                                 const float* __restrict__ cw,
                                                 const float* __restrict__ cb,
                                                 const float* __restrict__ Wx,
                                                 float* __restrict__ hs,
                                                 float* __restrict__ sp) {
    int l0 = blockIdx.x * 32, d0 = blockIdx.y * 64, b = blockIdx.z;
    __shared__ float xs[35][68];
    __shared__ float cs[32][68];
    __shared__ float wxs[64][48];
    int tid = threadIdx.x;
    for (int idx = tid; idx < 35 * 16; idx += 256) {
        int r = idx >> 4, q = idx & 15;
        int l = l0 - 3 + r;
        float4 v = {0.f, 0.f, 0.f, 0.f};
        if (l >= 0) v = *(const float4*)(xg + ((size_t)(b * LQ + l)) * 1024 + d0 + q * 4);
        *(float4*)&xs[r][q * 4] = v;
    }
    for (int idx = tid; idx < 64 * 12; idx += 256) {
        int r = idx / 12, q = idx % 12;
        *(float4*)&wxs[r][q * 4] = *(const float4*)(Wx + (size_t)(d0 + r) * 48 + q * 4);
    }
    __syncthreads();
    int dl = tid >> 2, lq = tid & 3;
    const float* w = cw + (d0 + dl) * KC;
    float w0 = w[0], w1 = w[1], w2 = w[2], w3 = w[3];
    float bb = cb[d0 + dl];
    float out[8];
    float x0 = xs[lq * 8 + 0][dl];
    float x1 = xs[lq * 8 + 1][dl];
    float x2 = xs[lq * 8 + 2][dl];
#pragma unroll
    for (int j = 0; j < 8; ++j) {
        float x3 = xs[lq * 8 + 3 + j][dl];
        float v = fmaf(w0, x0, fmaf(w1, x1, fmaf(w2, x2, fmaf(w3, x3, bb))));
        out[j] = siluf_(v);
        x0 = x1; x1 = x2; x2 = x3;
    }
#pragma unroll
    for (int j = 0; j < 8; ++j) cs[lq * 8 + j][dl] = out[j];
    __syncthreads();
    // hs write (coalesced)
    for (int idx = tid; idx < 32 * 16; idx += 256) {
        int r = idx >> 4, q = idx & 15;
        *(float4*)(hs + ((size_t)(b * LQ + l0 + r)) * DI + d0 + q * 4) =
            *(const float4*)&cs[r][q * 4];
    }
    // sp partials: 32 l x 48 j, 64-d dot each
    for (int o = tid; o < 32 * 48; o += 256) {
        int l = o / 48, j = o % 48;
        float acc = 0.f;
#pragma unroll
        for (int dq = 0; dq < 16; ++dq) {
            float4 cv = *(const float4*)&cs[l][dq * 4];
            acc = fmaf(cv.x, wxs[dq * 4 + 0][j], acc);
            acc = fmaf(cv.y, wxs[dq * 4 + 1][j], acc);
            acc = fmaf(cv.z, wxs[dq * 4 + 2][j], acc);
            acc = fmaf(cv.w, wxs[dq * 4 + 3][j], acc);
        }
        atomicAdd(&sp[((size_t)(b * LQ) + l0 + l) * 48 + j], acc);
    }
}

// ---------------- scan phase A: thread per d, 16 states in regs, chunk of 32 l, fused delta
__global__ __launch_bounds__(256) void k_scanA(const float* __restrict__ hs,
                                               const float* __restrict__ sp,
                                               const float* __restrict__ Wdt,
                                               const float* __restrict__ bdt,
                                               const float* __restrict__ Alog,
                                               float* __restrict__ PS) {
    int c = blockIdx.x, b = blockIdx.z;
    int t = threadIdx.x;
    int d = blockIdx.y * 256 + t;
    __shared__ float sps[32][48];
    for (int o = t; o < 32 * 12; o += 256) {
        int l = o / 12, q = o % 12;
        *(float4*)&sps[l][q * 4] =
            *(const float4*)(sp + ((size_t)(b * LQ) + c * 32 + l) * 48 + q * 4);
    }
    float wd[16];
#pragma unroll
    for (int k = 0; k < 16; ++k) wd[k] = Wdt[k * DI + d];
    float bv = bdt[d];
    float Av[16];
    {
        const float4* ap = (const float4*)(Alog + (size_t)d * 16);
#pragma unroll
        for (int i = 0; i < 4; i++) {
            float4 v = ap[i];
            Av[4 * i + 0] = -expf(v.x);
            Av[4 * i + 1] = -expf(v.y);
            Av[4 * i + 2] = -expf(v.z);
            Av[4 * i + 3] = -expf(v.w);
        }
    }
    __syncthreads();
    float hst[16], P[16];
#pragma unroll
    for (int n = 0; n < 16; n++) { hst[n] = 0.f; P[n] = 1.f; }
    const float* up = hs + ((size_t)(b * LQ) + c * 32) * DI + d;
#pragma unroll 2
    for (int l = 0; l < 32; ++l) {
        float u = up[(size_t)l * DI];
        float4 t0 = *(const float4*)&sps[l][0];
        float4 t1 = *(const float4*)&sps[l][4];
        float4 t2 = *(const float4*)&sps[l][8];
        float4 t3 = *(const float4*)&sps[l][12];
        float acc = bv;
        acc = fmaf(t0.x, wd[0], acc);  acc = fmaf(t0.y, wd[1], acc);
        acc = fmaf(t0.z, wd[2], acc);  acc = fmaf(t0.w, wd[3], acc);
        acc = fmaf(t1.x, wd[4], acc);  acc = fmaf(t1.y, wd[5], acc);
        acc = fmaf(t1.z, wd[6], acc);  acc = fmaf(t1.w, wd[7], acc);
        acc = fmaf(t2.x, wd[8], acc);  acc = fmaf(t2.y, wd[9], acc);
        acc = fmaf(t2.z, wd[10], acc); acc = fmaf(t2.w, wd[11], acc);
        acc = fmaf(t3.x, wd[12], acc); acc = fmaf(t3.y, wd[13], acc);
        acc = fmaf(t3.z, wd[14], acc); acc = fmaf(t3.w, wd[15], acc);
        float delta = softplusf_(acc);
        float du = delta * u;
#pragma unroll
        for (int n = 0; n < 16; n++) {
            float dA = __expf(delta * Av[n]);
            hst[n] = fmaf(dA, hst[n], du * sps[l][16 + n]);
            P[n] *= dA;
        }
    }
    float* pb = PS + ((size_t)(b * 32 + c)) * (32 * DI) + d;
#pragma unroll
    for (int n = 0; n < 16; n++) {
        pb[(2 * n) * DI] = P[n];
        pb[(2 * n + 1) * DI] = hst[n];
    }
}

// ---------------- scan phase B: serial combine over 32 chunks; hin overwrites P slot
__global__ void k_scanB(float* __restrict__ PS) {
    int idx = blockIdx.x * 256 + threadIdx.x;  // 32768 = b*8192 + n*512 + d
    int b = idx >> 13;
    int r = idx & 8191;
    float run = 0.f;
#pragma unroll 4
    for (int c = 0; c < 32; c++) {
        size_t o = ((size_t)(b * 32 + c)) * (32 * DI) + 2 * (size_t)r;
        size_t oP = ((size_t)(b * 32 + c)) * (32 * DI) + ((r >> 9) * 2) * DI + (r & 511);
        float P = PS[oP];
        float hl = PS[oP + DI];
        PS[oP] = run;
        run = fmaf(P, run, hl);
        (void)o;
    }
}

// ---------------- scan phase C: replay chunk from hin, fused delta, emit y bf16 hi/lo
__global__ __launch_bounds__(256) void k_scanC(const float* __restrict__ hs,
                                               const float* __restrict__ sp,
                                               const float* __restrict__ xg,
                                               const float* __restrict__ PS,
                                               const float* __restrict__ Wdt,
                                               const float* __restrict__ bdt,
                                               const float* __restrict__ Alog,
                                               const float* __restrict__ Dsk,
                                               bf16* __restrict__ yh, bf16* __restrict__ yl) {
    int c = blockIdx.x, b = blockIdx.z;
    int t = threadIdx.x;
    int d = blockIdx.y * 256 + t;
    __shared__ float sps[32][48];
    for (int o = t; o < 32 * 12; o += 256) {
        int l = o / 12, q = o % 12;
        *(float4*)&sps[l][q * 4] =
            *(const float4*)(sp + ((size_t)(b * LQ) + c * 32 + l) * 48 + q * 4);
    }
    float wd[16];
#pragma unroll
    for (int k = 0; k < 16; ++k) wd[k] = Wdt[k * DI + d];
    float bv = bdt[d];
    float Av[16];
    {
        const float4* ap = (const float4*)(Alog + (size_t)d * 16);
#pragma unroll
        for (int i = 0; i < 4; i++) {
            float4 v = ap[i];
            Av[4 * i + 0] = -expf(v.x);
            Av[4 * i + 1] = -expf(v.y);
            Av[4 * i + 2] = -expf(v.z);
            Av[4 * i + 3] = -expf(v.w);
        }
    }
    float Dv = Dsk[d];
    float hst[16];
    {
        const float* pb = PS + ((size_t)(b * 32 + c)) * (32 * DI) + d;
#pragma unroll
        for (int n = 0; n < 16; n++) hst[n] = pb[(2 * n) * DI];
    }
    __syncthreads();
    const float* up = hs + ((size_t)(b * LQ) + c * 32) * DI + d;
    const float* gp = xg + ((size_t)(b * LQ) + c * 32) * 1024 + DI + d;
    bf16* yhp = yh + ((size_t)(b * LQ) + c * 32) * DI + d;
    bf16* ylp = yl + ((size_t)(b * LQ) + c * 32) * DI + d;
#pragma unroll 2
    for (int l = 0; l < 32; ++l) {
        float u = up[(size_t)l * DI];
        float gv = gp[(size_t)l * 1024];
        float4 t0 = *(const float4*)&sps[l][0];
        float4 t1 = *(const float4*)&sps[l][4];
        float4 t2 = *(const float4*)&sps[l][8];
        float4 t3 = *(const float4*)&sps[l][12];
        float acc = bv;
        acc = fmaf(t0.x, wd[0], acc);  acc = fmaf(t0.y, wd[1], acc);
        acc = fmaf(t0.z, wd[2], acc);  acc = fmaf(t0.w, wd[3], acc);
        acc = fmaf(t1.x, wd[4], acc);  acc = fmaf(t1.y, wd[5], acc);
        acc = fmaf(t1.z, wd[6], acc);  acc = fmaf(t1.w, wd[7], acc);
        acc = fmaf(t2.x, wd[8], acc);  acc = fmaf(t2.y, wd[9], acc);
        acc = fmaf(t2.z, wd[10], acc); acc = fmaf(t2.w, wd[11], acc);
        acc = fmaf(t3.x, wd[12], acc); acc = fmaf(t3.y, wd[13], acc);
        acc = fmaf(t3.z, wd[14], acc); acc = fmaf(t3.w, wd[15], acc);
        float delta = softplusf_(acc);
        float du = delta * u;
        float p = 0.f;
#pragma unroll
        for (int n = 0; n < 16; n++) {
            float dA = __expf(delta * Av[n]);
            hst[n] = fmaf(dA, hst[n], du * sps[l][16 + n]);
            p = fmaf(hst[n], sps[l][32 + n], p);
        }
        float yv = (p + u * Dv) * gv * sigmoidf_(gv);
        bf16 hb, lb;
        cvt_hilo(yv, hb, lb);
        yhp[(size_t)l * DI] = hb;
        ylp[(size_t)l * DI] = lb;
    }
}

// ---------------- head
__global__ __launch_bounds__(256) void k_head(const float* __restrict__ h,
                                              const float* __restrict__ Wa,
                                              const float* __restrict__ ba,
                                              const float* __restrict__ Wp,
                                              const float* __restrict__ bp,
                                              float* __restrict__ out) {
    int row = blockIdx.x * 4 + (threadIdx.x >> 6);
    int lane = threadIdx.x & 63;
    float4 v = ((const float4*)(h + (size_t)row * DM))[lane];
    float4 wa = ((const float4*)Wa)[lane];
    float4 wp = ((const float4*)Wp)[lane];
    float sa = v.x * wa.x + v.y * wa.y + v.z * wa.z + v.w * wa.w;
    float sph = v.x * wp.x + v.y * wp.y + v.z * wp.z + v.w * wp.w;
#pragma unroll
    for (int off = 32; off; off >>= 1) {
        sa += __shfl_xor(sa, off);
        sph += __shfl_xor(sph, off);
    }
    if (lane == 0) {
        out[(size_t)row * 2 + 0] = sa + ba[0];
        out[(size_t)row * 2 + 1] = tanhf(sph + bp[0]);
    }
}

extern "C" void kernel_launch(void* const* d_in, const int* in_sizes, int n_in,
                              void* d_out, int out_size, void* d_ws, size_t ws_size,
                              hipStream_t stream) {
    const float* x = (const float*)d_in[0];
    const float* pos = (const float*)d_in[1];
    const float* We = (const float*)d_in[2];
    const float* be = (const float*)d_in[3];
    const float* ln_w = (const float*)d_in[4];
    const float* W_in = (const float*)d_in[5];
    const float* conv_w = (const float*)d_in[6];
    const float* conv_b = (const float*)d_in[7];
    const float* W_x = (const float*)d_in[8];
    const float* W_dt = (const float*)d_in[9];
    const float* b_dt = (const float*)d_in[10];
    const float* A_log = (const float*)d_in[11];
    const float* D_skip = (const float*)d_in[12];
    const float* W_out = (const float*)d_in[13];
    const float* Wa = (const float*)d_in[14];
    const float* ba = (const float*)d_in[15];
    const float* Wp = (const float*)d_in[16];
    const float* bp = (const float*)d_in[17];

    float* ws = (float*)d_ws;
    float* h = ws;                         // 1,048,576 f
    float* xg = h + 1048576;               // 4,194,304 f
    float* hs = xg + 4194304;              // 2,097,152 f
    float* sp = hs + 2097152;              // 196,608 f
    float* PS = sp + 196608;               // 2,097,152 f
    bf16* xn_hi = (bf16*)(PS + 2097152);   // 1,048,576 bf16
    bf16* xn_lo = xn_hi + 1048576;
    bf16* y_hi = xn_lo + 1048576;          // 2,097,152 bf16
    bf16* y_lo = y_hi + 2097152;
    bf16* wtin_h = y_lo + 2097152;         // 2,097,152 bf16
    bf16* wtin_l = wtin_h + 2097152;
    bf16* wtout_h = wtin_l + 2097152;      // 1,048,576 bf16
    bf16* wtout_l = wtout_h + 1048576;

    k_wt<<<dim3(8, 32, 8), 256, 0, stream>>>(W_in, wtin_h, wtin_l, 256, 1024);
    k_wt<<<dim3(16, 8, 8), 256, 0, stream>>>(W_out, wtout_h, wtout_l, 512, 256);
    k_embed<<<4096, 256, 0, stream>>>(x, pos, We, be, h);
    for (int i = 0; i < NL; i++) {
        k_rmsnorm<<<1024, 256, 0, stream>>>(h, ln_w + i * DM, xn_hi, xn_lo);
        k_gemm_bf3<0><<<dim3(16, 64), 256, 0, stream>>>(
            xn_hi, xn_lo, wtin_h + (size_t)i * 1024 * 256, wtin_l + (size_t)i * 1024 * 256,
            nullptr, xg, 4096, 1024, 256);
        k_zero<<<192, 256, 0, stream>>>(sp);
        k_conv_sp<<<dim3(32, 8, 4), 256, 0, stream>>>(xg, conv_w + i * DI * KC,
                                                      conv_b + i * DI,
                                                      W_x + (size_t)i * DI * 48, hs, sp);
        k_scanA<<<dim3(32, 2, 4), 256, 0, stream>>>(hs, sp, W_dt + i * DTR * DI,
                                                    b_dt + i * DI, A_log + i * DI * NS, PS);
        k_scanB<<<128, 256, 0, stream>>>(PS);
        k_scanC<<<dim3(32, 2, 4), 256, 0, stream>>>(hs, sp, xg, PS, W_dt + i * DTR * DI,
                                                    b_dt + i * DI, A_log + i * DI * NS,
                                                    D_skip + i * DI, y_hi, y_lo);
        k_gemm_bf3<1><<<dim3(4, 64), 256, 0, stream>>>(
            y_hi, y_lo, wtout_h + (size_t)i * 256 * 512, wtout_l + (size_t)i * 256 * 512,
            h, h, 4096, 256, 512);
    }
    k_head<<<1024, 256, 0, stream>>>(h, Wa, ba, Wp, bp, (float*)d_out);
}